// Round 7
// baseline (401.883 us; speedup 1.0000x reference)
//
#include <hip/hip_runtime.h>
#include <math.h>

// (T,B,C,H,W) = (9,8,256,56,56), fp32.
// Round 7: DRAM-row-locality design. Measured ladder (rounds 0-6): 16B
// segments -> 1.0 TB/s, 32B -> 2.2, single 128B lines @12.5KB stride -> ~3.5
// (rounds 5/6), sequential -> 6.7. HBM pays a row-activate per discontiguous
// line; only multi-KB contiguity reaches ~6.6 TB/s. The softmax-over-t dep
// forces staging (strided) or double-read (sequential); sequential double-
// read wins: ~503 MB @ ~6.4 TB/s < 231 MB @ 3.5 + serialization.
// Three chained dispatches, every wave-load 1KB contiguous, all fp32:
//  A scores: block=(t,b,cg): reads 16 c-rows = 200KB CONTIGUOUS, register
//    c-accumulation, writes px-partials into d_out-as-scratch (3.6MB of
//    25.7MB; consumed by B before C overwrites out).
//  B softmax: reduce 16 partials per (t,b,px), softmax over t, attn -> d_ws.
//  C attend: thread-linear over out: 9 sequential seq streams + L2-hot attn
//    + sequential stores. Block order REVERSED so C reads A's most-recently
//    cached data first: 231MB < 256MB L3 -> re-read largely L3-sourced.
// Math note (validated rounds 0-6): score_center and bias are constant
// along softmax axis t -> shift-invariant -> dropped.
#define TT 9
#define BN 8
#define CC 256
#define HW 3136
#define HW4 (HW / 4)        // 784 float4 per row
#define CG 16               // c-groups
#define CPG (CC / CG)       // 16 c per group
#define CENTER_T 4
#define TSTRIDE ((size_t)BN * CC * HW)  // seq t-stride = 6422528 floats

// ---------- Kernel A: partial scores, fully sequential reads ----------
__global__ __launch_bounds__(256) void scores_kernel(
    const float* __restrict__ seq, const float* __restrict__ w,
    float* __restrict__ scratch) {
  const int blk = blockIdx.x;          // 0..1151
  const int t = blk >> 7;              // /128
  const int b = (blk >> 4) & 7;
  const int cg = blk & 15;
  const int tid = threadIdx.x;

  __shared__ float wsh[CPG];
  if (tid < CPG) wsh[tid] = w[CC + cg * CPG + tid];
  __syncthreads();

  const float* base =
      seq + (((size_t)t * BN + b) * CC + cg * CPG) * HW;  // 16 rows, 200KB contig

  float4 acc[4];
#pragma unroll
  for (int k = 0; k < 4; ++k) acc[k] = make_float4(0.f, 0.f, 0.f, 0.f);

  for (int j = 0; j < CPG; ++j) {
    const float wj = wsh[j];
    const float* rp = base + (size_t)j * HW;
#pragma unroll
    for (int k = 0; k < 4; ++k) {
      const int q = tid + 256 * k;     // float4 index in row
      if (k < 3 || tid < HW4 - 768) {  // 784 = 3*256 + 16
        const float4 v = *(const float4*)(rp + 4 * q);
        acc[k].x = fmaf(wj, v.x, acc[k].x);
        acc[k].y = fmaf(wj, v.y, acc[k].y);
        acc[k].z = fmaf(wj, v.z, acc[k].z);
        acc[k].w = fmaf(wj, v.w, acc[k].w);
      }
    }
  }
  float* op = scratch + (size_t)blk * HW;  // partial[t][b][cg][px]
#pragma unroll
  for (int k = 0; k < 4; ++k) {
    const int q = tid + 256 * k;
    if (k < 3 || tid < HW4 - 768) *(float4*)(op + 4 * q) = acc[k];
  }
}

// ---------- Kernel B: reduce partials + softmax over t ----------
__global__ __launch_bounds__(256) void softmax_kernel(
    const float* __restrict__ scratch, float* __restrict__ attn) {
  const int i = blockIdx.x * 256 + threadIdx.x;  // 0..25087 = b*HW + px
  if (i >= BN * HW) return;
  const int b = i / HW;
  const int px = i - b * HW;

  float sc[TT];
  float m = -1e30f;
#pragma unroll
  for (int t = 0; t < TT; ++t) {
    float s = 0.f;
#pragma unroll
    for (int cg = 0; cg < CG; ++cg)
      s += scratch[(size_t)((t * BN + b) * CG + cg) * HW + px];
    sc[t] = s;
    m = fmaxf(m, s);
  }
  float sum = 0.f;
#pragma unroll
  for (int t = 0; t < TT; ++t) { sc[t] = __expf(sc[t] - m); sum += sc[t]; }
  const float inv = 1.f / sum;
#pragma unroll
  for (int t = 0; t < TT; ++t)
    attn[(size_t)(t * BN + b) * HW + px] = sc[t] * inv;
}

// ---------- Kernel C: attend, 9 sequential streams, reversed order ----------
__global__ __launch_bounds__(256) void attend_kernel(
    const float* __restrict__ seq, const float* __restrict__ attn,
    const float* __restrict__ gamma, float* __restrict__ out) {
  // reversed block order: first blocks read what kernel A cached last (L3)
  const int rb = gridDim.x - 1 - blockIdx.x;
  const int i = rb * 256 + threadIdx.x;   // float4 index over out, 0..1605631
  const int b = i / (CC * HW4);
  const int rem = i - b * (CC * HW4);
  const int c = rem / HW4;
  const int q = rem - c * HW4;

  const float* sp = seq + ((size_t)b * CC + c) * HW + 4 * q;
  const float* ap = attn + (size_t)b * HW + 4 * q;   // + t*(BN*HW)

  float4 v[TT], a[TT];
#pragma unroll
  for (int t = 0; t < TT; ++t) v[t] = *(const float4*)(sp + t * TSTRIDE);
#pragma unroll
  for (int t = 0; t < TT; ++t)
    a[t] = *(const float4*)(ap + (size_t)t * (BN * HW));

  float4 o = make_float4(0.f, 0.f, 0.f, 0.f);
#pragma unroll
  for (int t = 0; t < TT; ++t) {
    o.x = fmaf(a[t].x, v[t].x, o.x);
    o.y = fmaf(a[t].y, v[t].y, o.y);
    o.z = fmaf(a[t].z, v[t].z, o.z);
    o.w = fmaf(a[t].w, v[t].w, o.w);
  }
  const float gm = gamma[0];
  float4 r;
  r.x = fmaf(gm, o.x, v[CENTER_T].x);
  r.y = fmaf(gm, o.y, v[CENTER_T].y);
  r.z = fmaf(gm, o.z, v[CENTER_T].z);
  r.w = fmaf(gm, o.w, v[CENTER_T].w);
  *(float4*)(out + ((size_t)b * CC + c) * HW + 4 * q) = r;
}

extern "C" void kernel_launch(void* const* d_in, const int* in_sizes, int n_in,
                              void* d_out, int out_size, void* d_ws, size_t ws_size,
                              hipStream_t stream) {
  const float* seq = (const float*)d_in[0];
  const float* w = (const float*)d_in[1];
  // d_in[2] (bias) unused: softmax shift-invariant.
  const float* gamma = (const float*)d_in[3];
  float* out = (float*)d_out;
  float* attn = (float*)d_ws;            // 903 KB in workspace
  float* scratch = out;                  // 3.6 MB of out used as A->B scratch

  scores_kernel<<<TT * BN * CG, 256, 0, stream>>>(seq, w, scratch);
  softmax_kernel<<<(BN * HW + 255) / 256, 256, 0, stream>>>(scratch, attn);
  attend_kernel<<<(BN * CC * HW4) / 256, 256, 0, stream>>>(seq, attn, gamma, out);
}